// Round 1
// baseline (37851.675 us; speedup 1.0000x reference)
//
#include <hip/hip_runtime.h>
#include <cstddef>

#define BB 32
#define TT 2048
#define DD 512
#define LL 512
#define NBLK 32
#define HSZ ((size_t)BB * TT * LL)

typedef __attribute__((ext_vector_type(8))) short short8;
typedef __attribute__((ext_vector_type(4))) float floatx4;

__device__ __forceinline__ unsigned short f2bf(float f) {
  __bf16 b = (__bf16)f;
  return __builtin_bit_cast(unsigned short, b);
}

__device__ __forceinline__ short8 pack2(const float4& a, const float4& b) {
  short8 r;
  r[0] = (short)f2bf(a.x); r[1] = (short)f2bf(a.y);
  r[2] = (short)f2bf(a.z); r[3] = (short)f2bf(a.w);
  r[4] = (short)f2bf(b.x); r[5] = (short)f2bf(b.y);
  r[6] = (short)f2bf(b.z); r[7] = (short)f2bf(b.w);
  return r;
}

__device__ __forceinline__ float sigm(float v) {
  return 1.0f / (1.0f + __expf(-v));
}
__device__ __forceinline__ float tanh_f(float v) {
  return 1.0f - 2.0f / (__expf(2.0f * v) + 1.0f);
}

// 32 persistent blocks; block j owns l-columns [j*16, j*16+16) for ALL batches.
// Gate GEMM mapping: D[m=gatecol][n=batch] = A[m][k] * B[k][n],
//   A = W^T (resident in registers), B = [x_t | h_{t-1}] in bf16.
// 16 waves = (strip s: i/f/o/mem) x (k-group kg: 2 x-groups, 2 h-groups).
// h exchanged between blocks via agent-scope atomics on a MALL-coherent
// double-buffered bf16 buffer in d_ws, gated by per-block step flags.
__global__ __launch_bounds__(1024) void lstm_persistent(
    const float* __restrict__ x, const float* __restrict__ h0p,
    const float* __restrict__ c0p, const float* __restrict__ w_w,
    const float* __restrict__ w_b, const float* __restrict__ m_w,
    const float* __restrict__ m_b, float* __restrict__ out,
    unsigned int* flags, unsigned short* hbuf) {
  const int j = blockIdx.x;
  const int tid = threadIdx.x;
  const int wave = tid >> 6;
  const int lane = tid & 63;
  const int s = wave & 3;    // 0=i, 1=f, 2=o, 3=mem strip
  const int kg = wave >> 2;  // 0,1 = x half (k 0..511); 2,3 = h half
  const int q = lane >> 4;
  const int ln = lane & 15;

  __shared__ float partials[16][16][33];  // [s*4+kg][m(16)][n(32)+pad]

  // ---- preload A fragments: W^T slice, 8 k-tiles of 32, one m-tile of 16 ----
  short8 afrag[8];
  {
    const float* Wsrc;
    int wstride, col;
    if (s < 3) { Wsrc = w_w; wstride = 3 * LL; col = s * LL + j * 16 + ln; }
    else       { Wsrc = m_w; wstride = LL;     col = j * 16 + ln; }
#pragma unroll
    for (int kt = 0; kt < 8; ++kt) {
      const int kb = kg * 256 + kt * 32 + q * 8;
      short8 f;
#pragma unroll
      for (int jj = 0; jj < 8; ++jj)
        f[jj] = (short)f2bf(Wsrc[(size_t)(kb + jj) * wstride + col]);
      afrag[kt] = f;
    }
  }

  // ---- epilogue thread state: tid<256 -> (batch eb, l-pair elp) ----
  const int eb = tid >> 3;
  const int elp = tid & 7;
  const int ecol = j * 16 + elp * 2;
  float cc0 = 0.f, cc1 = 0.f;
  float bi0 = 0, bi1 = 0, bfg0 = 0, bfg1 = 0, bo0 = 0, bo1 = 0, bm0 = 0, bm1 = 0;
  if (tid < 256) {
    cc0 = c0p[eb * LL + ecol];
    cc1 = c0p[eb * LL + ecol + 1];
    bi0 = w_b[ecol];            bi1 = w_b[ecol + 1];
    bfg0 = w_b[LL + ecol];      bfg1 = w_b[LL + ecol + 1];
    bo0 = w_b[2 * LL + ecol];   bo1 = w_b[2 * LL + ecol + 1];
    bm0 = m_b[ecol];            bm1 = m_b[ecol + 1];
  }

  unsigned int* hbuf32 = (unsigned int*)hbuf;
  unsigned long long* hbuf64 = (unsigned long long*)hbuf;

#pragma unroll 1
  for (int t = 1; t <= TT; ++t) {
    floatx4 acc0 = {0.f, 0.f, 0.f, 0.f};
    floatx4 acc1 = {0.f, 0.f, 0.f, 0.f};

    if (kg < 2) {
      // x contribution (independent of recurrence; hides under h-wave wait)
      const size_t row0 = ((size_t)ln * TT + (t - 1)) * DD;
      const size_t row1 = ((size_t)(16 + ln) * TT + (t - 1)) * DD;
      const int kb0 = kg * 256 + q * 8;
      short8 bA[8], bB[8];
#pragma unroll
      for (int kt = 0; kt < 8; ++kt) {
        const int k = kb0 + kt * 32;
        float4 a0 = *(const float4*)(x + row0 + k);
        float4 a1 = *(const float4*)(x + row0 + k + 4);
        float4 c0v = *(const float4*)(x + row1 + k);
        float4 c1v = *(const float4*)(x + row1 + k + 4);
        bA[kt] = pack2(a0, a1);
        bB[kt] = pack2(c0v, c1v);
      }
#pragma unroll
      for (int kt = 0; kt < 8; ++kt) {
        acc0 = __builtin_amdgcn_mfma_f32_16x16x32_bf16(afrag[kt], bA[kt], acc0, 0, 0, 0);
        acc1 = __builtin_amdgcn_mfma_f32_16x16x32_bf16(afrag[kt], bB[kt], acc1, 0, 0, 0);
      }
    } else {
      // h contribution
      const int kh0 = (kg - 2) * 256 + q * 8;
      short8 bA[8], bB[8];
      if (t == 1) {
#pragma unroll
        for (int kt = 0; kt < 8; ++kt) {
          const int kh = kh0 + kt * 32;
          float4 a0 = *(const float4*)(h0p + ln * LL + kh);
          float4 a1 = *(const float4*)(h0p + ln * LL + kh + 4);
          float4 c0v = *(const float4*)(h0p + (16 + ln) * LL + kh);
          float4 c1v = *(const float4*)(h0p + (16 + ln) * LL + kh + 4);
          bA[kt] = pack2(a0, a1);
          bB[kt] = pack2(c0v, c1v);
        }
      } else {
        // wait for all 32 blocks to have published h(t-1)  (flag = t)
        if (lane < 32) {
          const unsigned int tu = (unsigned int)t;
          while (__hip_atomic_load(&flags[lane], __ATOMIC_RELAXED,
                                   __HIP_MEMORY_SCOPE_AGENT) < tu)
            __builtin_amdgcn_s_sleep(1);
        }
        __builtin_amdgcn_fence(__ATOMIC_ACQUIRE, "agent");
        const unsigned long long* base =
            hbuf64 + (size_t)((t - 1) & 1) * (BB * LL / 4);
#pragma unroll
        for (int kt = 0; kt < 8; ++kt) {
          const int kh = kh0 + kt * 32;
          union { unsigned long long u[2]; short8 s8; } ua, ub;
          const unsigned long long* p0 = base + (ln * LL + kh) / 4;
          const unsigned long long* p1 = base + ((16 + ln) * LL + kh) / 4;
          ua.u[0] = __hip_atomic_load(p0, __ATOMIC_RELAXED, __HIP_MEMORY_SCOPE_AGENT);
          ua.u[1] = __hip_atomic_load(p0 + 1, __ATOMIC_RELAXED, __HIP_MEMORY_SCOPE_AGENT);
          ub.u[0] = __hip_atomic_load(p1, __ATOMIC_RELAXED, __HIP_MEMORY_SCOPE_AGENT);
          ub.u[1] = __hip_atomic_load(p1 + 1, __ATOMIC_RELAXED, __HIP_MEMORY_SCOPE_AGENT);
          bA[kt] = ua.s8;
          bB[kt] = ub.s8;
        }
      }
#pragma unroll
      for (int kt = 0; kt < 8; ++kt) {
        acc0 = __builtin_amdgcn_mfma_f32_16x16x32_bf16(afrag[kt], bA[kt], acc0, 0, 0, 0);
        acc1 = __builtin_amdgcn_mfma_f32_16x16x32_bf16(afrag[kt], bB[kt], acc1, 0, 0, 0);
      }
    }

    // K-partial write: D col = lane&15 (batch), row = q*4+r (gatecol)
    const int sg = s * 4 + kg;
#pragma unroll
    for (int r = 0; r < 4; ++r) {
      partials[sg][q * 4 + r][ln] = acc0[r];
      partials[sg][q * 4 + r][16 + ln] = acc1[r];
    }
    __syncthreads();

    if (tid < 256) {
      const int m0 = elp * 2, m1 = elp * 2 + 1;
      float gi0 = partials[0][m0][eb] + partials[1][m0][eb] + partials[2][m0][eb] + partials[3][m0][eb];
      float gi1 = partials[0][m1][eb] + partials[1][m1][eb] + partials[2][m1][eb] + partials[3][m1][eb];
      float gf0 = partials[4][m0][eb] + partials[5][m0][eb] + partials[6][m0][eb] + partials[7][m0][eb];
      float gf1 = partials[4][m1][eb] + partials[5][m1][eb] + partials[6][m1][eb] + partials[7][m1][eb];
      float go0 = partials[8][m0][eb] + partials[9][m0][eb] + partials[10][m0][eb] + partials[11][m0][eb];
      float go1 = partials[8][m1][eb] + partials[9][m1][eb] + partials[10][m1][eb] + partials[11][m1][eb];
      float gm0 = partials[12][m0][eb] + partials[13][m0][eb] + partials[14][m0][eb] + partials[15][m0][eb];
      float gm1 = partials[12][m1][eb] + partials[13][m1][eb] + partials[14][m1][eb] + partials[15][m1][eb];

      float i0 = sigm(gi0 + bi0), i1 = sigm(gi1 + bi1);
      float f0 = sigm(gf0 + bfg0), f1 = sigm(gf1 + bfg1);
      float o0 = sigm(go0 + bo0), o1 = sigm(go1 + bo1);
      float mm0 = tanh_f(gm0 + bm0), mm1 = tanh_f(gm1 + bm1);
      cc0 = f0 * cc0 + i0 * mm0;
      cc1 = f1 * cc1 + i1 * mm1;
      float hv0 = o0 * tanh_f(cc0);
      float hv1 = o1 * tanh_f(cc1);

      const size_t obase = ((size_t)eb * TT + (t - 1)) * LL + ecol;
      float2 hh; hh.x = hv0; hh.y = hv1;
      float2 cv; cv.x = cc0; cv.y = cc1;
      *(float2*)(out + obase) = hh;
      *(float2*)(out + HSZ + obase) = cv;

      union { unsigned short us[2]; unsigned int u32; } pk;
      pk.us[0] = f2bf(hv0);
      pk.us[1] = f2bf(hv1);
      __hip_atomic_store(
          hbuf32 + (size_t)(t & 1) * (BB * LL / 2) + ((size_t)eb * LL + ecol) / 2,
          pk.u32, __ATOMIC_RELAXED, __HIP_MEMORY_SCOPE_AGENT);
    }
    __syncthreads();  // drains vmcnt -> hbuf stores are at MALL before flag
    if (tid == 0)
      __hip_atomic_store(&flags[j], (unsigned int)(t + 1), __ATOMIC_RELEASE,
                         __HIP_MEMORY_SCOPE_AGENT);
  }
}

extern "C" void kernel_launch(void* const* d_in, const int* in_sizes, int n_in,
                              void* d_out, int out_size, void* d_ws, size_t ws_size,
                              hipStream_t stream) {
  const float* x   = (const float*)d_in[0];
  const float* h0  = (const float*)d_in[1];
  const float* c0  = (const float*)d_in[2];
  const float* w_w = (const float*)d_in[3];
  const float* w_b = (const float*)d_in[4];
  const float* m_w = (const float*)d_in[5];
  const float* m_b = (const float*)d_in[6];
  float* out = (float*)d_out;

  unsigned int* flags = (unsigned int*)d_ws;                      // 32 x u32
  unsigned short* hbuf = (unsigned short*)((char*)d_ws + 256);    // 2 x 32 x 512 bf16

  hipMemsetAsync(d_ws, 0, 256, stream);  // reset step flags (ws is poisoned 0xAA)
  hipLaunchKernelGGL(lstm_persistent, dim3(NBLK), dim3(1024), 0, stream,
                     x, h0, c0, w_w, w_b, m_w, m_b, out, flags, hbuf);
}

// Round 2
// 28369.144 us; speedup vs baseline: 1.3343x; 1.3343x over previous
//
#include <hip/hip_runtime.h>
#include <cstddef>

#define BB 32
#define TT 2048
#define DD 512
#define LL 512
#define NBLK 32
#define HSZ ((size_t)BB * TT * LL)
#define FSTRIDE 16   // u32 elements between per-block flags (64 B apart)
#define LDSROW 520   // bf16 elems per staged-h row (512 + 8 pad -> 2-way banks)

typedef __attribute__((ext_vector_type(8))) short short8;
typedef __attribute__((ext_vector_type(4))) float floatx4;

__device__ __forceinline__ unsigned short f2bf(float f) {
  __bf16 b = (__bf16)f;
  return __builtin_bit_cast(unsigned short, b);
}

__device__ __forceinline__ short8 pack2(const float4& a, const float4& b) {
  short8 r;
  r[0] = (short)f2bf(a.x); r[1] = (short)f2bf(a.y);
  r[2] = (short)f2bf(a.z); r[3] = (short)f2bf(a.w);
  r[4] = (short)f2bf(b.x); r[5] = (short)f2bf(b.y);
  r[6] = (short)f2bf(b.z); r[7] = (short)f2bf(b.w);
  return r;
}

__device__ __forceinline__ float sigm(float v) {
  return 1.0f / (1.0f + __expf(-v));
}
__device__ __forceinline__ float tanh_f(float v) {
  return 1.0f - 2.0f / (__expf(2.0f * v) + 1.0f);
}

// 32 persistent blocks; block j owns col-slice `slice` (XCD-paired swizzle so
// adjacent 64B output halves come from same-XCD blocks -> full-line L2 wb).
// Per step: x-waves (0-7) MFMA the x half; wave 8 alone polls the 32 flags;
// h staged hbuf->LDS once (plain dwordx4 after agent-acquire fence); h-waves
// MFMA from LDS; epilogue publishes bf16 h + release-adds flag BEFORE the
// HBM output stores so the store drain is off the critical path.
__global__ __launch_bounds__(1024, 4) void lstm_persistent(
    const float* __restrict__ x, const float* __restrict__ h0p,
    const float* __restrict__ c0p, const float* __restrict__ w_w,
    const float* __restrict__ w_b, const float* __restrict__ m_w,
    const float* __restrict__ m_b, float* __restrict__ out,
    unsigned int* flags, unsigned short* hbuf) {
  const int j = blockIdx.x;
  const int slice = ((j & 7) << 2) | (j >> 3);  // same-XCD blocks -> adjacent slices
  const int tid = threadIdx.x;
  const int wave = tid >> 6;
  const int lane = tid & 63;
  const int s = wave & 3;    // 0=i, 1=f, 2=o, 3=mem strip
  const int kg = wave >> 2;  // 0,1 = x half; 2,3 = h half
  const int q = lane >> 4;
  const int ln = lane & 15;

  __shared__ __align__(16) float partials[16][16][36];
  __shared__ __align__(16) unsigned short hstage[32 * LDSROW];

  // ---- preload A fragments: W^T slice (k rows 0..1023 = [x|h]) ----
  short8 afrag[8];
  {
    const float* Wsrc;
    int wstride, col;
    if (s < 3) { Wsrc = w_w; wstride = 3 * LL; col = s * LL + slice * 16 + ln; }
    else       { Wsrc = m_w; wstride = LL;     col = slice * 16 + ln; }
#pragma unroll
    for (int kt = 0; kt < 8; ++kt) {
      const int kb = kg * 256 + kt * 32 + q * 8;
      short8 f;
#pragma unroll
      for (int jj = 0; jj < 8; ++jj)
        f[jj] = (short)f2bf(Wsrc[(size_t)(kb + jj) * wstride + col]);
      afrag[kt] = f;
    }
  }

  // ---- epilogue thread state: tid<256 -> (batch eb, l-pair elp) ----
  const int eb = tid >> 3;
  const int elp = tid & 7;
  const int ecol = slice * 16 + elp * 2;
  float cc0 = 0.f, cc1 = 0.f;
  float bi0 = 0, bi1 = 0, bfg0 = 0, bfg1 = 0, bo0 = 0, bo1 = 0, bm0 = 0, bm1 = 0;
  if (tid < 256) {
    cc0 = c0p[eb * LL + ecol];
    cc1 = c0p[eb * LL + ecol + 1];
    bi0 = w_b[ecol];            bi1 = w_b[ecol + 1];
    bfg0 = w_b[LL + ecol];      bfg1 = w_b[LL + ecol + 1];
    bo0 = w_b[2 * LL + ecol];   bo1 = w_b[2 * LL + ecol + 1];
    bm0 = m_b[ecol];            bm1 = m_b[ecol + 1];
  }

  unsigned int* hbuf32 = (unsigned int*)hbuf;

#pragma unroll 1
  for (int t = 1; t <= TT; ++t) {
    floatx4 acc0 = {0.f, 0.f, 0.f, 0.f};
    floatx4 acc1 = {0.f, 0.f, 0.f, 0.f};

    if (kg < 2) {
      // ---- x contribution: independent of the recurrence ----
      const size_t row0 = ((size_t)ln * TT + (t - 1)) * DD;
      const size_t row1 = ((size_t)(16 + ln) * TT + (t - 1)) * DD;
      const int kb0 = kg * 256 + q * 8;
#pragma unroll
      for (int kt = 0; kt < 8; ++kt) {
        const int k = kb0 + kt * 32;
        float4 a0 = *(const float4*)(x + row0 + k);
        float4 a1 = *(const float4*)(x + row0 + k + 4);
        float4 c0v = *(const float4*)(x + row1 + k);
        float4 c1v = *(const float4*)(x + row1 + k + 4);
        short8 bA = pack2(a0, a1);
        short8 bB = pack2(c0v, c1v);
        acc0 = __builtin_amdgcn_mfma_f32_16x16x32_bf16(afrag[kt], bA, acc0, 0, 0, 0);
        acc1 = __builtin_amdgcn_mfma_f32_16x16x32_bf16(afrag[kt], bB, acc1, 0, 0, 0);
      }
      const int sg = s * 4 + kg;
#pragma unroll
      for (int r = 0; r < 4; ++r) {
        partials[sg][q * 4 + r][ln] = acc0[r];
        partials[sg][q * 4 + r][16 + ln] = acc1[r];
      }
    } else if (wave == 8 && t > 1 && lane < 32) {
      // ---- single poller: one coalesced load of 32 spread flags per iter ----
      const unsigned int need = 4u * (unsigned int)(t - 1);
      while (__hip_atomic_load(&flags[lane * FSTRIDE], __ATOMIC_RELAXED,
                               __HIP_MEMORY_SCOPE_AGENT) < need)
        __builtin_amdgcn_s_sleep(2);
    }
    __syncthreads();  // b1: all blocks' h(t-1) published

    if (kg >= 2) {
      // ---- stage h(t-1) into LDS: 512 threads x 64 B, no redundancy ----
      const int idx = tid - 512;
      const int b = idx & 31;
      const int g = idx >> 5;
      unsigned short* dst = &hstage[b * LDSROW + g * 32];
      if (t == 1) {
        const float* src = h0p + b * LL + g * 32;
#pragma unroll
        for (int i = 0; i < 4; ++i) {
          float4 a0 = *(const float4*)(src + i * 8);
          float4 a1 = *(const float4*)(src + i * 8 + 4);
          *(short8*)(dst + i * 8) = pack2(a0, a1);
        }
      } else {
        __builtin_amdgcn_fence(__ATOMIC_ACQUIRE, "agent");  // inv L1/L2
        const uint4* src =
            (const uint4*)(hbuf + (size_t)((t - 1) & 1) * (BB * LL) + b * LL + g * 32);
        uint4 v0 = src[0]; uint4 v1 = src[1];
        uint4 v2 = src[2]; uint4 v3 = src[3];
        uint4* d4 = (uint4*)dst;
        d4[0] = v0; d4[1] = v1; d4[2] = v2; d4[3] = v3;
      }
    }
    __syncthreads();  // b2: hstage ready

    if (kg >= 2) {
      const int kh0 = (kg - 2) * 256 + q * 8;
#pragma unroll
      for (int kt = 0; kt < 8; ++kt) {
        const int kh = kh0 + kt * 32;
        short8 bA = *(const short8*)&hstage[(size_t)ln * LDSROW + kh];
        short8 bB = *(const short8*)&hstage[(size_t)(16 + ln) * LDSROW + kh];
        acc0 = __builtin_amdgcn_mfma_f32_16x16x32_bf16(afrag[kt], bA, acc0, 0, 0, 0);
        acc1 = __builtin_amdgcn_mfma_f32_16x16x32_bf16(afrag[kt], bB, acc1, 0, 0, 0);
      }
      const int sg = s * 4 + kg;
#pragma unroll
      for (int r = 0; r < 4; ++r) {
        partials[sg][q * 4 + r][ln] = acc0[r];
        partials[sg][q * 4 + r][16 + ln] = acc1[r];
      }
    }
    __syncthreads();  // b3: all partials ready

    if (tid < 256) {
      const int m0 = elp * 2, m1 = elp * 2 + 1;
      float gi0 = partials[0][m0][eb] + partials[1][m0][eb] + partials[2][m0][eb] + partials[3][m0][eb];
      float gi1 = partials[0][m1][eb] + partials[1][m1][eb] + partials[2][m1][eb] + partials[3][m1][eb];
      float gf0 = partials[4][m0][eb] + partials[5][m0][eb] + partials[6][m0][eb] + partials[7][m0][eb];
      float gf1 = partials[4][m1][eb] + partials[5][m1][eb] + partials[6][m1][eb] + partials[7][m1][eb];
      float go0 = partials[8][m0][eb] + partials[9][m0][eb] + partials[10][m0][eb] + partials[11][m0][eb];
      float go1 = partials[8][m1][eb] + partials[9][m1][eb] + partials[10][m1][eb] + partials[11][m1][eb];
      float gm0 = partials[12][m0][eb] + partials[13][m0][eb] + partials[14][m0][eb] + partials[15][m0][eb];
      float gm1 = partials[12][m1][eb] + partials[13][m1][eb] + partials[14][m1][eb] + partials[15][m1][eb];

      float i0 = sigm(gi0 + bi0), i1 = sigm(gi1 + bi1);
      float f0 = sigm(gf0 + bfg0), f1 = sigm(gf1 + bfg1);
      float o0 = sigm(go0 + bo0), o1 = sigm(go1 + bo1);
      float mm0 = tanh_f(gm0 + bm0), mm1 = tanh_f(gm1 + bm1);
      cc0 = f0 * cc0 + i0 * mm0;
      cc1 = f1 * cc1 + i1 * mm1;
      float hv0 = o0 * tanh_f(cc0);
      float hv1 = o1 * tanh_f(cc1);

      // publish h first (critical path), signal, THEN the streaming outputs
      union { unsigned short us[2]; unsigned int u32; } pk;
      pk.us[0] = f2bf(hv0);
      pk.us[1] = f2bf(hv1);
      __hip_atomic_store(
          hbuf32 + (size_t)(t & 1) * (BB * LL / 2) + ((size_t)eb * LL + ecol) / 2,
          pk.u32, __ATOMIC_RELAXED, __HIP_MEMORY_SCOPE_AGENT);
      if (lane == 0)
        __hip_atomic_fetch_add(&flags[j * FSTRIDE], 1u, __ATOMIC_RELEASE,
                               __HIP_MEMORY_SCOPE_AGENT);  // waits only hbuf stores

      const size_t obase = ((size_t)eb * TT + (t - 1)) * LL + ecol;
      float2 hh; hh.x = hv0; hh.y = hv1;
      float2 cv; cv.x = cc0; cv.y = cc1;
      *(float2*)(out + obase) = hh;
      *(float2*)(out + HSZ + obase) = cv;
    }
    __syncthreads();  // b4: partials consumed; loop
  }
}

extern "C" void kernel_launch(void* const* d_in, const int* in_sizes, int n_in,
                              void* d_out, int out_size, void* d_ws, size_t ws_size,
                              hipStream_t stream) {
  const float* x   = (const float*)d_in[0];
  const float* h0  = (const float*)d_in[1];
  const float* c0  = (const float*)d_in[2];
  const float* w_w = (const float*)d_in[3];
  const float* w_b = (const float*)d_in[4];
  const float* m_w = (const float*)d_in[5];
  const float* m_b = (const float*)d_in[6];
  float* out = (float*)d_out;

  unsigned int* flags = (unsigned int*)d_ws;                       // 32 x u32, 64B apart
  unsigned short* hbuf = (unsigned short*)((char*)d_ws + 2048);    // 2 x 32 x 512 bf16

  hipMemsetAsync(d_ws, 0, 2048, stream);  // zero step flags (ws poisoned 0xAA)
  hipLaunchKernelGGL(lstm_persistent, dim3(NBLK), dim3(1024), 0, stream,
                     x, h0, c0, w_w, w_b, m_w, m_b, out, flags, hbuf);
}